// Round 4
// baseline (174.659 us; speedup 1.0000x reference)
//
#include <hip/hip_runtime.h>

#define LN 512        // MAX_IN_LENGTH (fixed by the reference)
#define NK 84         // number of base kernels = C(9,3)
#define THREADS 256
#define PH_ROWS 14    // rows per LDS staging phase
#define N_PH 6        // NK / PH_ROWS

// ---------------------------------------------------------------------------
// Fused kernel: one block per (bc, group).
//   * Wave 0 parses the group's dilation in-block (ballot probe of W row
//     g*84: first nonzero tap sits at 4*(maxd-d), a multiple of 4).
//   * out[o,t] = bias_g - S9 + 3*(ta+tb+tc), combos in lexicographic order.
//   * ROUND-4 EXPERIMENT: stage output in LDS (14 rows/phase), then drain as
//     perfectly linear 16B-aligned float4 stores — store stream becomes
//     shape-identical to the 6.4 TB/s fill kernel. Tests the theory that the
//     1800 B-row (64B-misaligned) direct stores caused partial-line/RFO
//     traffic ~2x the mandatory 141.5 MB.
//   * nt stores are known-bad here (R3: +18 us); stores go through L2.
// ---------------------------------------------------------------------------
__global__ __launch_bounds__(THREADS) void rocket_fused(
    const float* __restrict__ X, const float* __restrict__ W,
    const float* __restrict__ bias, float* __restrict__ out,
    int O, int K, int T, int maxd, int max_pad, int n_groups) {
    extern __shared__ float xs[];   // [0, lb0): pad|X|pad ; [lb0, lb0+PH_ROWS*T): lbuf
    __shared__ int s_d;

    const int g  = blockIdx.x % n_groups;
    const int bc = blockIdx.x / n_groups;

    // --- dilation probe (wave 0 only), overlapped with LDS staging ---
    if (threadIdx.x < 64) {
        const int j = threadIdx.x;
        const float* row = W + (size_t)g * NK * K;
        float v = (j <= maxd && 4 * j < K) ? row[4 * j] : 0.0f;
        unsigned long long m = __ballot(v != 0.0f);
        if (j == 0) s_d = maxd - (__ffsll(m) - 1);   // d = (max_pad - 4*j0)/4
    }

    for (int i = threadIdx.x; i < max_pad; i += THREADS) {
        xs[i] = 0.0f;
        xs[max_pad + LN + i] = 0.0f;
    }
    const float* xrow = X + (size_t)bc * LN;
    for (int i = threadIdx.x; i < LN; i += THREADS) {
        xs[max_pad + i] = xrow[i];
    }
    __syncthreads();

    const int   d  = s_d;
    const float bv = bias[(size_t)g * NK];    // constant across the 84 channels
    float* const outg = out + ((size_t)bc * O + (size_t)g * NK) * T;
    const int pairs = T >> 1;

    if (pairs <= THREADS && (T & 1) == 0) {
        // ---- fast path: LDS-staged, linear float4 drain ----
        const int lb0 = LN + 2 * max_pad + 4;     // 1020 floats; 16B-aligned
        float* const lbuf = xs + lb0;
        const int n4 = (PH_ROWS * T) >> 2;        // 1575 float4 per phase

        // persistent taps (one t-pair per thread)
        float tx[9], ty[9];
        float bx = 0.0f, by = 0.0f;
        const bool active = (int)threadIdx.x < pairs;
        const int t0 = 2 * threadIdx.x;
        if (active) {
            const int base = max_pad + t0 - 4 * d;
            float s9x = 0.0f, s9y = 0.0f;
#pragma unroll
            for (int j = 0; j < 9; ++j) {
                tx[j] = xs[base + j * d];
                ty[j] = xs[base + j * d + 1];
                s9x += tx[j];
                s9y += ty[j];
            }
            bx = bv - s9x;
            by = bv - s9y;
        }

#pragma unroll
        for (int ph = 0; ph < N_PH; ++ph) {
            const int R0 = ph * PH_ROWS;
            if (active) {
                int k = 0;
#pragma unroll
                for (int a = 0; a < 7; ++a) {
#pragma unroll
                    for (int b2 = a + 1; b2 < 8; ++b2) {
                        const float px = tx[a] + tx[b2];
                        const float py = ty[a] + ty[b2];
#pragma unroll
                        for (int c = b2 + 1; c < 9; ++c, ++k) {
                            if (k >= R0 && k < R0 + PH_ROWS) {
                                float* w = lbuf + (k - R0) * T + t0;
                                *(float2*)w = make_float2(
                                    fmaf(3.0f, px + tx[c], bx),
                                    fmaf(3.0f, py + ty[c], by));
                            }
                        }
                    }
                }
            }
            __syncthreads();
            // linear 16B-aligned drain: identical shape to the fill kernel
            float4* const dst = (float4*)(outg + R0 * T);
            const float4* const src = (const float4*)lbuf;
            for (int i = threadIdx.x; i < n4; i += THREADS)
                dst[i] = src[i];
            __syncthreads();
        }
    } else {
        // ---- generic fallback (round-2 form): direct strided stores ----
        for (int p = threadIdx.x; p < pairs; p += THREADS) {
            const int t0   = 2 * p;
            const int base = max_pad + t0 - 4 * d;
            float tx[9], ty[9];
            float s9x = 0.0f, s9y = 0.0f;
#pragma unroll
            for (int j = 0; j < 9; ++j) {
                tx[j] = xs[base + j * d];
                ty[j] = xs[base + j * d + 1];
                s9x += tx[j];
                s9y += ty[j];
            }
            const float bx = bv - s9x;
            const float by = bv - s9y;
            float* op = outg + t0;
#pragma unroll
            for (int a = 0; a < 7; ++a) {
#pragma unroll
                for (int b2 = a + 1; b2 < 8; ++b2) {
                    const float px = tx[a] + tx[b2];
                    const float py = ty[a] + ty[b2];
#pragma unroll
                    for (int c = b2 + 1; c < 9; ++c) {
                        *(float2*)op = make_float2(fmaf(3.0f, px + tx[c], bx),
                                                   fmaf(3.0f, py + ty[c], by));
                        op += T;
                    }
                }
            }
        }
        if ((T & 1) && threadIdx.x == 0) {
            const int t    = T - 1;
            const int base = max_pad + t - 4 * d;
            float tx[9]; float s9 = 0.0f;
#pragma unroll
            for (int j = 0; j < 9; ++j) { tx[j] = xs[base + j * d]; s9 += tx[j]; }
            const float bx = bv - s9;
            float* op = outg + t;
            for (int a = 0; a < 7; ++a)
                for (int b2 = a + 1; b2 < 8; ++b2)
                    for (int c = b2 + 1; c < 9; ++c) {
                        *op = fmaf(3.0f, tx[a] + tx[b2] + tx[c], bx);
                        op += T;
                    }
        }
    }
}

extern "C" void kernel_launch(void* const* d_in, const int* in_sizes, int n_in,
                              void* d_out, int out_size, void* d_ws, size_t ws_size,
                              hipStream_t stream) {
    const float* X = (const float*)d_in[0];
    const float* W = (const float*)d_in[1];
    const float* b = (const float*)d_in[2];
    float* out = (float*)d_out;

    const int O        = in_sizes[2];           // 3276
    const int K        = in_sizes[1] / O;       // 567
    const int maxd     = K / 9;                 // 63
    const int max_pad  = 4 * maxd;              // 252
    const int BC       = in_sizes[0] / LN;      // 24
    const int T        = out_size / (BC * O);   // 450
    const int n_groups = O / NK;                // 39

    // xs (LN + 2*max_pad + 4 floats) + lbuf (PH_ROWS*T floats) + slack
    const size_t smem =
        (size_t)(LN + 2 * max_pad + 4 + PH_ROWS * T + 4) * sizeof(float);
    rocket_fused<<<BC * n_groups, THREADS, smem, stream>>>(
        X, W, b, out, O, K, T, maxd, max_pad, n_groups);
}

// Round 5
// 160.264 us; speedup vs baseline: 1.0898x; 1.0898x over previous
//
#include <hip/hip_runtime.h>

#define LN 512        // MAX_IN_LENGTH (fixed by the reference)
#define NK 84         // number of base kernels = C(9,3)
#define THREADS 256

// ---------------------------------------------------------------------------
// Round 5: float4 (dwordx4) store experiment.
// One block per (bc, group); two halves of 128 threads each own 42 of the 84
// combo rows (template<HALF> folds the combo range at compile time). Each
// active thread computes 4 consecutive t's and emits 42 float4 stores:
// 16 B/lane, 1024 B contiguous per wave-store (vs 512 B dwordx2 before) —
// halves store-instruction count and line fragmentation per instruction.
// Known-bad variants: nt stores (R3 +18us), LDS-staged drain (R4 +25us).
// ---------------------------------------------------------------------------

template <int HALF>
__device__ __forceinline__ void emit_rows(const float (&tt)[4][9],
                                          const float (&bq)[4],
                                          float* __restrict__ op, int T,
                                          bool quad) {
    constexpr int K0 = HALF * 42;
    constexpr int K1 = K0 + 42;
    int k = 0;   // folds to a compile-time constant under full unroll
#pragma unroll
    for (int a = 0; a < 7; ++a) {
#pragma unroll
        for (int b = a + 1; b < 8; ++b) {
            float p0 = 0.f, p1 = 0.f, p2 = 0.f, p3 = 0.f;
            if (k + (8 - b) > K0 && k < K1) {   // (a,b) group intersects range
                p0 = tt[0][a] + tt[0][b];
                p1 = tt[1][a] + tt[1][b];
                p2 = tt[2][a] + tt[2][b];
                p3 = tt[3][a] + tt[3][b];
            }
#pragma unroll
            for (int c = b + 1; c < 9; ++c) {
                if (k >= K0 && k < K1) {
                    const float q0 = fmaf(3.0f, p0 + tt[0][c], bq[0]);
                    const float q1 = fmaf(3.0f, p1 + tt[1][c], bq[1]);
                    if (quad) {
                        const float q2 = fmaf(3.0f, p2 + tt[2][c], bq[2]);
                        const float q3 = fmaf(3.0f, p3 + tt[3][c], bq[3]);
                        *(float4*)op = make_float4(q0, q1, q2, q3);
                    } else {
                        *(float2*)op = make_float2(q0, q1);
                    }
                    op += T;
                }
                ++k;
            }
        }
    }
}

__global__ __launch_bounds__(THREADS) void rocket_fused(
    const float* __restrict__ X, const float* __restrict__ W,
    const float* __restrict__ bias, float* __restrict__ out,
    int O, int K, int T, int maxd, int max_pad, int n_groups) {
    extern __shared__ float xs[];   // max_pad | LN | max_pad (zero-padded edges)
    __shared__ int s_d;

    const int g  = blockIdx.x % n_groups;
    const int bc = blockIdx.x / n_groups;

    // --- dilation probe (wave 0 only), overlapped with LDS staging ---
    if (threadIdx.x < 64) {
        const int j = threadIdx.x;
        const float* row = W + (size_t)g * NK * K;
        float v = (j <= maxd && 4 * j < K) ? row[4 * j] : 0.0f;
        unsigned long long m = __ballot(v != 0.0f);
        if (j == 0) s_d = maxd - (__ffsll(m) - 1);   // d = (max_pad - 4*j0)/4
    }

    for (int i = threadIdx.x; i < max_pad; i += THREADS) {
        xs[i] = 0.0f;
        xs[max_pad + LN + i] = 0.0f;
    }
    const float* xrow = X + (size_t)bc * LN;
    for (int i = threadIdx.x; i < LN; i += THREADS) {
        xs[max_pad + i] = xrow[i];
    }
    __syncthreads();

    const int   d  = s_d;
    const float bv = bias[(size_t)g * NK];    // constant across the 84 channels
    float* const outg = out + ((size_t)bc * O + (size_t)g * NK) * T;

    const int Q = T >> 2;                      // full float4 quads per row
    if ((T & 1) == 0 && Q <= 126) {
        // ---- fast path: two 128-thread halves, 42 rows each, float4 stores --
        const int half = threadIdx.x >> 7;     // 0 or 1
        const int i    = threadIdx.x & 127;
        const bool quad = i < Q;
        const bool pair = (i == Q) && ((T & 3) == 2);
        if (quad || pair) {
            const int t0   = 4 * i;
            const int base = max_pad + t0 - 4 * d;
            float tt[4][9];
            float s0 = 0.f, s1 = 0.f, s2 = 0.f, s3 = 0.f;
#pragma unroll
            for (int j = 0; j < 9; ++j) {
                const float* xp = xs + base + j * d;
                tt[0][j] = xp[0]; tt[1][j] = xp[1];
                tt[2][j] = xp[2]; tt[3][j] = xp[3];   // in-bounds even for tail
                s0 += tt[0][j]; s1 += tt[1][j];
                s2 += tt[2][j]; s3 += tt[3][j];
            }
            float bq[4] = { bv - s0, bv - s1, bv - s2, bv - s3 };
            float* op = outg + (half * 42) * T + t0;
            if (half == 0) emit_rows<0>(tt, bq, op, T, quad);
            else           emit_rows<1>(tt, bq, op, T, quad);
        }
    } else {
        // ---- generic fallback (round-2 form): direct strided float2 stores --
        const int pairs = T >> 1;
        for (int p = threadIdx.x; p < pairs; p += THREADS) {
            const int t0   = 2 * p;
            const int base = max_pad + t0 - 4 * d;
            float tx[9], ty[9];
            float s9x = 0.0f, s9y = 0.0f;
#pragma unroll
            for (int j = 0; j < 9; ++j) {
                tx[j] = xs[base + j * d];
                ty[j] = xs[base + j * d + 1];
                s9x += tx[j];
                s9y += ty[j];
            }
            const float bx = bv - s9x;
            const float by = bv - s9y;
            float* op = outg + t0;
#pragma unroll
            for (int a = 0; a < 7; ++a) {
#pragma unroll
                for (int b2 = a + 1; b2 < 8; ++b2) {
                    const float px = tx[a] + tx[b2];
                    const float py = ty[a] + ty[b2];
#pragma unroll
                    for (int c = b2 + 1; c < 9; ++c) {
                        *(float2*)op = make_float2(fmaf(3.0f, px + tx[c], bx),
                                                   fmaf(3.0f, py + ty[c], by));
                        op += T;
                    }
                }
            }
        }
        if ((T & 1) && threadIdx.x == 0) {
            const int t    = T - 1;
            const int base = max_pad + t - 4 * d;
            float tx[9]; float s9 = 0.0f;
#pragma unroll
            for (int j = 0; j < 9; ++j) { tx[j] = xs[base + j * d]; s9 += tx[j]; }
            const float bx = bv - s9;
            float* op = outg + t;
            for (int a = 0; a < 7; ++a)
                for (int b2 = a + 1; b2 < 8; ++b2)
                    for (int c = b2 + 1; c < 9; ++c) {
                        *op = fmaf(3.0f, tx[a] + tx[b2] + tx[c], bx);
                        op += T;
                    }
        }
    }
}

extern "C" void kernel_launch(void* const* d_in, const int* in_sizes, int n_in,
                              void* d_out, int out_size, void* d_ws, size_t ws_size,
                              hipStream_t stream) {
    const float* X = (const float*)d_in[0];
    const float* W = (const float*)d_in[1];
    const float* b = (const float*)d_in[2];
    float* out = (float*)d_out;

    const int O        = in_sizes[2];           // 3276
    const int K        = in_sizes[1] / O;       // 567
    const int maxd     = K / 9;                 // 63
    const int max_pad  = 4 * maxd;              // 252
    const int BC       = in_sizes[0] / LN;      // 24
    const int T        = out_size / (BC * O);   // 450
    const int n_groups = O / NK;                // 39

    const size_t smem = (size_t)(LN + 2 * max_pad + 4) * sizeof(float);
    rocket_fused<<<BC * n_groups, THREADS, smem, stream>>>(
        X, W, b, out, O, K, T, maxd, max_pad, n_groups);
}